// Round 5
// baseline (174.810 us; speedup 1.0000x reference)
//
#include <hip/hip_runtime.h>

typedef unsigned long long u64;

constexpr int D = 48, H = 384, W = 384;
constexpr int WPR = 6;                    // 384 bits / 64 per row
constexpr int NVOX = D * H * W;           // 7,077,888
constexpr int NWVOL = D * H * WPR;        // 110,592 packed words per volume
constexpr int MPAD = 40;                  // padded word-change-mask size: 1 pad + 36 + 3 pad

// full adder: s = a+b+c (bit-sliced), cy = carry
__device__ __forceinline__ void fa(u64 a, u64 b, u64 c, u64& s, u64& cy) {
  u64 x = a ^ b;
  s = x ^ c;
  cy = (a & b) | (c & x);
}

// One Zhang-Suen subiteration for one packed word (64 pixels).
// buf is an R x WPR bit image in LDS, zero-padded implicitly at borders.
template<int R>
__device__ __forceinline__ u64 zs_word(const u64* buf, int idx, int r, int wc, bool first) {
  const u64 img = buf[idx];
  if (!img) return 0;                     // removal subset of img
  u64 w00 = 0, w01 = 0, w02 = 0, w10 = 0, w12 = 0, w20 = 0, w21 = 0, w22 = 0;
  const u64 w11 = img;
  const bool rm = (r > 0), rp = (r < R - 1);
  const bool cm = (wc > 0), cp = (wc < WPR - 1);
  if (rm) {
    w01 = buf[idx - WPR];
    if (cm) w00 = buf[idx - WPR - 1];
    if (cp) w02 = buf[idx - WPR + 1];
  }
  if (cm) w10 = buf[idx - 1];
  if (cp) w12 = buf[idx + 1];
  if (rp) {
    w21 = buf[idx + WPR];
    if (cm) w20 = buf[idx + WPR - 1];
    if (cp) w22 = buf[idx + WPR + 1];
  }
  // bit j = column wc*64+j. east (c+1) -> (w>>1)|(next<<63), west (c-1) -> (w<<1)|(prev>>63)
  const u64 P2 = w01;                          // N
  const u64 P3 = (w01 >> 1) | (w02 << 63);     // NE
  const u64 P4 = (w11 >> 1) | (w12 << 63);     // E
  const u64 P5 = (w21 >> 1) | (w22 << 63);     // SE
  const u64 P6 = w21;                          // S
  const u64 P7 = (w21 << 1) | (w20 >> 63);     // SW
  const u64 P8 = (w11 << 1) | (w10 >> 63);     // W
  const u64 P9 = (w01 << 1) | (w00 >> 63);     // NW

  u64 s1, c1, s2, c2, s3, c3, u0, u1, v1, v2;
  fa(P2, P3, P4, s1, c1);
  fa(P5, P6, P7, s2, c2);
  fa(P8, P9, 0ull, s3, c3);
  fa(s1, s2, s3, u0, u1);
  fa(c1, c2, c3, v1, v2);
  u64 b1 = u1 ^ v1, k2 = u1 & v1;
  u64 b2 = v2 ^ k2, b3 = v2 & k2;
  u64 condB = (b1 | b2 | b3) & ~(b3 | (b2 & b1 & u0));   // 2<=B<=6

  u64 t0 = ~P2 & P3, t1 = ~P3 & P4, t2 = ~P4 & P5, t3 = ~P5 & P6;
  u64 t4 = ~P6 & P7, t5 = ~P7 & P8, t6 = ~P8 & P9, t7 = ~P9 & P2;
  fa(t0, t1, t2, s1, c1);
  fa(t3, t4, t5, s2, c2);
  fa(t6, t7, 0ull, s3, c3);
  fa(s1, s2, s3, u0, u1);
  fa(c1, c2, c3, v1, v2);
  u64 a1 = u1 ^ v1, j2 = u1 & v1;
  u64 a2 = v2 ^ j2, a3 = v2 & j2;
  u64 condA = u0 & ~(a1 | a2 | a3);                      // A == 1

  u64 cc = first ? ((~(P2 & P4 & P6)) & (~(P4 & P6 & P8)))
                 : ((~(P2 & P4 & P8)) & (~(P2 & P6 & P8)));
  return img & ~(condB & condA & cc);
}

// Test 3 bits (word indices q..q+2) of the padded word-change mask U.
// Padded layout: logical word i lives at bit position 64+i; U[0]/tail are zero pads.
__device__ __forceinline__ bool dirty3(const u64* U, int q) {
  const int pb = q + 64;              // q >= -64 always
  const int w = pb >> 6, sh = pb & 63;
  u64 v = U[w] >> sh;
  if (sh > 61) v |= U[w + 1] << (64 - sh);
  return (v & 7ull) != 0;
}

// One pruned subiteration pass. Word-granular dirty masks built via ballot
// (threads in a wave handle 64 consecutive, 64-aligned words -> ballot IS the mask word).
template<int R, bool FIRST>
__device__ __forceinline__ void subpass(const u64* __restrict__ src, u64* __restrict__ dst,
                                        u64* rawW, const u64* rawPrev,
                                        u64* Uw, const u64* Ur,
                                        int* chgflag, int tid, int nthr) {
  constexpr int NW = R * WPR;
  int anych = 0;
  for (int base = 0; base < NW; base += nthr) {
    const int idx = base + tid;
    int changed = 0;
    if (idx < NW) {
      const int r = idx / WPR, wc = idx - r * WPR;
      const u64 old = src[idx];
      u64 nw = old;
      const bool dirty = dirty3(Ur, idx - 1)
                       | dirty3(Ur, idx - WPR - 1)
                       | dirty3(Ur, idx + WPR - 1);
      if (dirty) {
        nw = zs_word<R>(src, idx, r, wc, FIRST);
        changed = (nw != old);
      }
      dst[idx] = nw;
      anych |= changed;
    }
    const u64 bal = __ballot(changed != 0);
    if ((tid & 63) == 0 && idx < NW) {
      const int mw = 1 + (idx >> 6);
      rawW[mw] = bal;
      Uw[mw] = bal | rawPrev[mw];
    }
  }
  if (anych) *chgflag = 1;
}

// MODE 0: slice=z, rows r=y, cols=x  -> atomicOr words into skelZY (packed x)
// MODE 1: slice=y, rows r=z, cols=x  -> atomicOr words into skelZY (packed x)
// MODE 2: slice=x, rows r=z, cols=y  -> per-set-bit atomicOr into skelZY (transposed scatter)
template<int R, int MODE>
__device__ __forceinline__ void thin_body(const u64* __restrict__ maskP,
                                          u64* __restrict__ skelZY,
                                          int slice, u64* Abuf, u64* Bbuf,
                                          u64 (*raw)[MPAD], u64 (*Um)[MPAD],
                                          int* s_chg) {
  constexpr int NW = R * WPR;
  constexpr int MW = (NW + 63) >> 6;    // logical mask words
  const int tid = threadIdx.x;
  const int nthr = blockDim.x;

  // ---- load packed slice into LDS ----
  if (MODE == 0) {
    for (int idx = tid; idx < NW; idx += nthr) {
      int r = idx / WPR, wc = idx - r * WPR;
      Abuf[idx] = maskP[(slice * H + r) * WPR + wc];
    }
  } else if (MODE == 1) {
    for (int idx = tid; idx < NW; idx += nthr) {
      int r = idx / WPR, wc = idx - r * WPR;
      Abuf[idx] = maskP[(r * H + slice) * WPR + wc];
    }
  } else {
    const int lane = tid & 63, wave = tid >> 6, nwv = nthr >> 6;
    const int xw = slice >> 6, xb = slice & 63;
    for (int idx = wave; idx < NW; idx += nwv) {
      int r = idx / WPR, wc = idx - r * WPR;
      int c = wc * 64 + lane;                     // c = y
      u64 bit = (maskP[(r * H + c) * WPR + xw] >> xb) & 1ull;
      u64 w = __ballot(bit != 0);
      if (lane == 0) Abuf[idx] = w;
    }
  }

  // init masks: ones in logical range (forces first two passes all-dirty), zero pads
  for (int t = tid; t < 4 * MPAD; t += nthr) {
    const int arr = t / MPAD, j = t - arr * MPAD;
    const u64 v = (j >= 1 && j <= MW) ? ~0ull : 0ull;
    if (arr < 2) raw[arr][j] = v; else Um[arr - 2][j] = v;
  }
  if (tid < 2) s_chg[tid] = 0;
  __syncthreads();

  // ---- iterate Zhang-Suen to convergence, word-pruned; 2 barriers/iter ----
  int k = 0;
  while (true) {
    subpass<R, true >(Abuf, Bbuf, raw[0], raw[1], Um[0], Um[1], &s_chg[k], tid, nthr);
    __syncthreads();
    if (tid == 0) s_chg[k ^ 1] = 0;   // prep next iter's slot; subpass2 touches slot k only
    subpass<R, false>(Bbuf, Abuf, raw[1], raw[0], Um[1], Um[0], &s_chg[k], tid, nthr);
    __syncthreads();
    if (s_chg[k] == 0) break;
    k ^= 1;
  }

  // ---- writeback ----
  if (MODE == 2) {
    const int xw = slice >> 6;
    const u64 xbit = 1ull << (slice & 63);
    for (int idx = tid; idx < NW; idx += nthr) {
      u64 w = Abuf[idx];
      const int z = idx / WPR, yw = idx - z * WPR;
      while (w) {
        const int b = __builtin_ctzll(w);
        w &= w - 1;
        atomicOr(&skelZY[(z * H + (yw * 64 + b)) * WPR + xw], xbit);
      }
    }
  } else {
    for (int idx = tid; idx < NW; idx += nthr) {
      u64 w = Abuf[idx];
      if (!w) continue;                            // target zero-initialized
      int r = idx / WPR, wc = idx - r * WPR;
      if (MODE == 0) atomicOr(&skelZY[(slice * H + r) * WPR + wc], w);
      else           atomicOr(&skelZY[(r * H + slice) * WPR + wc], w);
    }
  }
}

__global__ __launch_bounds__(1024) void thin_all(const u64* __restrict__ maskP,
                                                 u64* __restrict__ skelZY) {
  __shared__ u64 Abuf[H * WPR];       // sized for the largest mode (z-slices)
  __shared__ u64 Bbuf[H * WPR];
  __shared__ u64 raw[2][MPAD];
  __shared__ u64 Um[2][MPAD];
  __shared__ int s_chg[2];
  const int b = blockIdx.x;
  if (b < D) {
    thin_body<H, 0>(maskP, skelZY, b, Abuf, Bbuf, raw, Um, s_chg);
  } else if (b < D + H) {
    thin_body<D, 1>(maskP, skelZY, b - D, Abuf, Bbuf, raw, Um, s_chg);
  } else {
    thin_body<D, 2>(maskP, skelZY, b - D - H, Abuf, Bbuf, raw, Um, s_chg);
  }
}

// Pack mask bits (v==1.0f) along x; zero the skeleton accumulator.
__global__ void init_pack(const float* __restrict__ in, u64* __restrict__ maskP,
                          u64* __restrict__ skelZY) {
  const int lane = threadIdx.x & 63;
  const int gwave = (blockIdx.x * blockDim.x + threadIdx.x) >> 6;
  const int nwaves = (gridDim.x * blockDim.x) >> 6;
  for (int widx = gwave; widx < NWVOL; widx += nwaves) {
    float v = in[(size_t)widx * 64 + lane];
    u64 w = __ballot(v == 1.0f);
    if (lane == 0) {
      maskP[widx] = w;
      skelZY[widx] = 0;
    }
  }
}

// Word-parallel 6-connected dilation + mask + expand to float4.
__global__ void dilate_expand(const u64* __restrict__ maskP,
                              const u64* __restrict__ skelZY,
                              float* __restrict__ out) {
  const int idx = blockIdx.x * blockDim.x + threadIdx.x;   // one float4 per thread
  if (idx >= NVOX / 4) return;
  const int i4 = idx * 4;
  const int wi = i4 >> 6;
  const int wc = wi % WPR;
  const int row = wi / WPR;        // row = z*H + y
  const int y = row % H;
  const int z = row / H;

  const u64 S = skelZY[wi];
  const u64 L = (wc > 0) ? skelZY[wi - 1] : 0ull;
  const u64 Rw = (wc < WPR - 1) ? skelZY[wi + 1] : 0ull;
  u64 d = S | (S << 1) | (L >> 63) | (S >> 1) | (Rw << 63);
  if (y > 0)     d |= skelZY[wi - WPR];
  if (y < H - 1) d |= skelZY[wi + WPR];
  if (z > 0)     d |= skelZY[wi - H * WPR];
  if (z < D - 1) d |= skelZY[wi + H * WPR];
  const u64 r = d & maskP[wi];

  const int sh = i4 & 63;
  float4 o;
  o.x = (float)((r >> (sh + 0)) & 1ull);
  o.y = (float)((r >> (sh + 1)) & 1ull);
  o.z = (float)((r >> (sh + 2)) & 1ull);
  o.w = (float)((r >> (sh + 3)) & 1ull);
  *reinterpret_cast<float4*>(out + i4) = o;
}

extern "C" void kernel_launch(void* const* d_in, const int* in_sizes, int n_in,
                              void* d_out, int out_size, void* d_ws, size_t ws_size,
                              hipStream_t stream) {
  const float* in = (const float*)d_in[0];
  float* out = (float*)d_out;
  u64* wsw = (u64*)d_ws;                 // need 2 * 110592 * 8 B = 1.77 MB
  u64* maskP = wsw;
  u64* skelZY = wsw + NWVOL;

  init_pack<<<1728, 256, 0, stream>>>(in, maskP, skelZY);
  thin_all<<<D + H + W, 1024, 0, stream>>>(maskP, skelZY);
  dilate_expand<<<(NVOX / 4 + 255) / 256, 256, 0, stream>>>(maskP, skelZY, out);
}

// Round 6
// 70.417 us; speedup vs baseline: 2.4825x; 2.4825x over previous
//
#include <hip/hip_runtime.h>

typedef unsigned long long u64;

constexpr int D = 48, H = 384, W = 384;
constexpr int WPR = 6;                    // 384 bits / 64 per row
constexpr int NVOX = D * H * W;           // 7,077,888
constexpr int NWVOL = D * H * WPR;        // 110,592 packed words per volume
constexpr int MPAD = 40;                  // padded word-change-mask size: 1 pad + 36 + 3 pad

// full adder: s = a+b+c (bit-sliced), cy = carry
__device__ __forceinline__ void fa(u64 a, u64 b, u64 c, u64& s, u64& cy) {
  u64 x = a ^ b;
  s = x ^ c;
  cy = (a & b) | (c & x);
}

// One Zhang-Suen subiteration for one packed word (64 pixels).
// buf is an R x WPR bit image in LDS, zero-padded implicitly at borders.
template<int R>
__device__ __forceinline__ u64 zs_word(const u64* buf, int idx, int r, int wc, bool first) {
  const u64 img = buf[idx];
  if (!img) return 0;                     // removal subset of img
  u64 w00 = 0, w01 = 0, w02 = 0, w10 = 0, w12 = 0, w20 = 0, w21 = 0, w22 = 0;
  const u64 w11 = img;
  const bool rm = (r > 0), rp = (r < R - 1);
  const bool cm = (wc > 0), cp = (wc < WPR - 1);
  if (rm) {
    w01 = buf[idx - WPR];
    if (cm) w00 = buf[idx - WPR - 1];
    if (cp) w02 = buf[idx - WPR + 1];
  }
  if (cm) w10 = buf[idx - 1];
  if (cp) w12 = buf[idx + 1];
  if (rp) {
    w21 = buf[idx + WPR];
    if (cm) w20 = buf[idx + WPR - 1];
    if (cp) w22 = buf[idx + WPR + 1];
  }
  // bit j = column wc*64+j. east (c+1) -> (w>>1)|(next<<63), west (c-1) -> (w<<1)|(prev>>63)
  const u64 P2 = w01;                          // N
  const u64 P3 = (w01 >> 1) | (w02 << 63);     // NE
  const u64 P4 = (w11 >> 1) | (w12 << 63);     // E
  const u64 P5 = (w21 >> 1) | (w22 << 63);     // SE
  const u64 P6 = w21;                          // S
  const u64 P7 = (w21 << 1) | (w20 >> 63);     // SW
  const u64 P8 = (w11 << 1) | (w10 >> 63);     // W
  const u64 P9 = (w01 << 1) | (w00 >> 63);     // NW

  u64 s1, c1, s2, c2, s3, c3, u0, u1, v1, v2;
  fa(P2, P3, P4, s1, c1);
  fa(P5, P6, P7, s2, c2);
  fa(P8, P9, 0ull, s3, c3);
  fa(s1, s2, s3, u0, u1);
  fa(c1, c2, c3, v1, v2);
  u64 b1 = u1 ^ v1, k2 = u1 & v1;
  u64 b2 = v2 ^ k2, b3 = v2 & k2;
  u64 condB = (b1 | b2 | b3) & ~(b3 | (b2 & b1 & u0));   // 2<=B<=6

  u64 t0 = ~P2 & P3, t1 = ~P3 & P4, t2 = ~P4 & P5, t3 = ~P5 & P6;
  u64 t4 = ~P6 & P7, t5 = ~P7 & P8, t6 = ~P8 & P9, t7 = ~P9 & P2;
  fa(t0, t1, t2, s1, c1);
  fa(t3, t4, t5, s2, c2);
  fa(t6, t7, 0ull, s3, c3);
  fa(s1, s2, s3, u0, u1);
  fa(c1, c2, c3, v1, v2);
  u64 a1 = u1 ^ v1, j2 = u1 & v1;
  u64 a2 = v2 ^ j2, a3 = v2 & j2;
  u64 condA = u0 & ~(a1 | a2 | a3);                      // A == 1

  u64 cc = first ? ((~(P2 & P4 & P6)) & (~(P4 & P6 & P8)))
                 : ((~(P2 & P4 & P8)) & (~(P2 & P6 & P8)));
  return img & ~(condB & condA & cc);
}

// Test 3 bits (word indices q..q+2) of the padded word-change mask U.
// Padded layout: logical word i lives at bit position 64+i; U[0]/tail are zero pads.
__device__ __forceinline__ bool dirty3(const u64* U, int q) {
  const int pb = q + 64;              // q >= -64 always
  const int w = pb >> 6, sh = pb & 63;
  u64 v = U[w] >> sh;
  if (sh > 61) v |= U[w + 1] << (64 - sh);
  return (v & 7ull) != 0;
}

// One pruned subiteration pass. Word-granular dirty masks built via ballot
// (threads in a wave handle 64 consecutive, 64-aligned words -> ballot IS the mask word).
template<int R, bool FIRST>
__device__ __forceinline__ void subpass(const u64* __restrict__ src, u64* __restrict__ dst,
                                        u64* rawW, const u64* rawPrev,
                                        u64* Uw, const u64* Ur,
                                        int* chgflag, int tid, int nthr) {
  constexpr int NW = R * WPR;
  int anych = 0;
  for (int base = 0; base < NW; base += nthr) {
    const int idx = base + tid;
    int changed = 0;
    if (idx < NW) {
      const int r = idx / WPR, wc = idx - r * WPR;
      const u64 old = src[idx];
      u64 nw = old;
      const bool dirty = dirty3(Ur, idx - 1)
                       | dirty3(Ur, idx - WPR - 1)
                       | dirty3(Ur, idx + WPR - 1);
      if (dirty) {
        nw = zs_word<R>(src, idx, r, wc, FIRST);
        changed = (nw != old);
      }
      dst[idx] = nw;
      anych |= changed;
    }
    const u64 bal = __ballot(changed != 0);
    if ((tid & 63) == 0 && idx < NW) {
      const int mw = 1 + (idx >> 6);
      rawW[mw] = bal;
      Uw[mw] = bal | rawPrev[mw];
    }
  }
  if (anych) *chgflag = 1;
}

// MODE 0: slice=z, rows r=y, cols=x  -> atomicOr into skelZY (packed x)
// MODE 1: slice=y, rows r=z, cols=x  -> atomicOr into skelZY (packed x)
// MODE 2: slice=x, rows r=z, cols=y  -> store to skelX (packed y, layout [z][x][yw], exclusive)
template<int R, int MODE>
__device__ __forceinline__ void thin_body(const u64* __restrict__ maskP,
                                          u64* __restrict__ skelZY,
                                          u64* __restrict__ skelX,
                                          int slice, u64* Abuf, u64* Bbuf,
                                          u64 (*raw)[MPAD], u64 (*Um)[MPAD],
                                          int* s_chg) {
  constexpr int NW = R * WPR;
  constexpr int MW = (NW + 63) >> 6;    // logical mask words
  const int tid = threadIdx.x;
  const int nthr = blockDim.x;

  // ---- load packed slice into LDS ----
  if (MODE == 0) {
    for (int idx = tid; idx < NW; idx += nthr) {
      int r = idx / WPR, wc = idx - r * WPR;
      Abuf[idx] = maskP[(slice * H + r) * WPR + wc];
    }
  } else if (MODE == 1) {
    for (int idx = tid; idx < NW; idx += nthr) {
      int r = idx / WPR, wc = idx - r * WPR;
      Abuf[idx] = maskP[(r * H + slice) * WPR + wc];
    }
  } else {
    const int lane = tid & 63, wave = tid >> 6, nwv = nthr >> 6;
    const int xw = slice >> 6, xb = slice & 63;
    for (int idx = wave; idx < NW; idx += nwv) {
      int r = idx / WPR, wc = idx - r * WPR;
      int c = wc * 64 + lane;                     // c = y
      u64 bit = (maskP[(r * H + c) * WPR + xw] >> xb) & 1ull;
      u64 w = __ballot(bit != 0);
      if (lane == 0) Abuf[idx] = w;
    }
  }

  // init masks: ones in logical range (forces first two passes all-dirty), zero pads
  for (int t = tid; t < 4 * MPAD; t += nthr) {
    const int arr = t / MPAD, j = t - arr * MPAD;
    const u64 v = (j >= 1 && j <= MW) ? ~0ull : 0ull;
    if (arr < 2) raw[arr][j] = v; else Um[arr - 2][j] = v;
  }
  if (tid < 2) s_chg[tid] = 0;
  __syncthreads();

  // ---- iterate Zhang-Suen to convergence, word-pruned; 2 barriers/iter ----
  int k = 0;
  while (true) {
    subpass<R, true >(Abuf, Bbuf, raw[0], raw[1], Um[0], Um[1], &s_chg[k], tid, nthr);
    __syncthreads();
    if (tid == 0) s_chg[k ^ 1] = 0;   // prep next iter's slot; subpass2 touches slot k only
    subpass<R, false>(Bbuf, Abuf, raw[1], raw[0], Um[1], Um[0], &s_chg[k], tid, nthr);
    __syncthreads();
    if (s_chg[k] == 0) break;
    k ^= 1;
  }

  // ---- writeback ----
  for (int idx = tid; idx < NW; idx += nthr) {
    u64 w = Abuf[idx];
    if (!w) continue;                              // targets are zero-initialized
    int r = idx / WPR, wc = idx - r * WPR;
    if (MODE == 0)      atomicOr(&skelZY[(slice * H + r) * WPR + wc], w);
    else if (MODE == 1) atomicOr(&skelZY[(r * H + slice) * WPR + wc], w);
    else                skelX[(r * W + slice) * WPR + wc] = w;
  }
}

__global__ __launch_bounds__(1024) void thin_all(const u64* __restrict__ maskP,
                                                 u64* __restrict__ skelZY,
                                                 u64* __restrict__ skelX) {
  __shared__ u64 Abuf[H * WPR];       // sized for the largest mode (z-slices)
  __shared__ u64 Bbuf[H * WPR];
  __shared__ u64 raw[2][MPAD];
  __shared__ u64 Um[2][MPAD];
  __shared__ int s_chg[2];
  const int b = blockIdx.x;
  if (b < D) {
    thin_body<H, 0>(maskP, skelZY, skelX, b, Abuf, Bbuf, raw, Um, s_chg);
  } else if (b < D + H) {
    thin_body<D, 1>(maskP, skelZY, skelX, b - D, Abuf, Bbuf, raw, Um, s_chg);
  } else {
    thin_body<D, 2>(maskP, skelZY, skelX, b - D - H, Abuf, Bbuf, raw, Um, s_chg);
  }
}

// Pack mask bits (v==1.0f) along x; zero the skeleton accumulators.
__global__ void init_pack(const float* __restrict__ in, u64* __restrict__ maskP,
                          u64* __restrict__ skelZY, u64* __restrict__ skelX) {
  const int lane = threadIdx.x & 63;
  const int gwave = (blockIdx.x * blockDim.x + threadIdx.x) >> 6;
  const int nwaves = (gridDim.x * blockDim.x) >> 6;
  for (int widx = gwave; widx < NWVOL; widx += nwaves) {
    float v = in[(size_t)widx * 64 + lane];
    u64 w = __ballot(v == 1.0f);
    if (lane == 0) {
      maskP[widx] = w;
      skelZY[widx] = 0;
      skelX[widx] = 0;
    }
  }
}

// Transpose skelX ([z][x][yw], packed y) into packed-x layout, OR into skelZY.
// One wave per 64x64 bit tile: z fixed, x = xw*64+lane, y = yw*64+j.
__global__ void transpose_or(const u64* __restrict__ skelX,
                             u64* __restrict__ skelZY) {
  const int gw = (blockIdx.x * blockDim.x + threadIdx.x) >> 6;   // tile id
  const int lane = threadIdx.x & 63;
  const int z = gw / 36, rem = gw - z * 36;
  const int yw = rem / 6, xw = rem - yw * 6;
  const int x = xw * 64 + lane;
  const u64 wx = skelX[(z * W + x) * WPR + yw];   // bits indexed by y
  u64 mine = 0;
  #pragma unroll 8
  for (int j = 0; j < 64; ++j) {
    u64 wj = __ballot((wx >> j) & 1ull);          // bit l = pixel(y=yw*64+j, x=xw*64+l)
    if (lane == j) mine = wj;
  }
  const int y = yw * 64 + lane;
  if (mine) skelZY[(z * H + y) * WPR + xw] |= mine;   // exclusive owner per word
}

// Word-parallel 6-connected dilation + mask + expand to float4.
__global__ void dilate_expand(const u64* __restrict__ maskP,
                              const u64* __restrict__ skelZY,
                              float* __restrict__ out) {
  const int idx = blockIdx.x * blockDim.x + threadIdx.x;   // one float4 per thread
  if (idx >= NVOX / 4) return;
  const int i4 = idx * 4;
  const int wi = i4 >> 6;
  const int wc = wi % WPR;
  const int row = wi / WPR;        // row = z*H + y
  const int y = row % H;
  const int z = row / H;

  const u64 S = skelZY[wi];
  const u64 L = (wc > 0) ? skelZY[wi - 1] : 0ull;
  const u64 Rw = (wc < WPR - 1) ? skelZY[wi + 1] : 0ull;
  u64 d = S | (S << 1) | (L >> 63) | (S >> 1) | (Rw << 63);
  if (y > 0)     d |= skelZY[wi - WPR];
  if (y < H - 1) d |= skelZY[wi + WPR];
  if (z > 0)     d |= skelZY[wi - H * WPR];
  if (z < D - 1) d |= skelZY[wi + H * WPR];
  const u64 r = d & maskP[wi];

  const int sh = i4 & 63;
  float4 o;
  o.x = (float)((r >> (sh + 0)) & 1ull);
  o.y = (float)((r >> (sh + 1)) & 1ull);
  o.z = (float)((r >> (sh + 2)) & 1ull);
  o.w = (float)((r >> (sh + 3)) & 1ull);
  *reinterpret_cast<float4*>(out + i4) = o;
}

extern "C" void kernel_launch(void* const* d_in, const int* in_sizes, int n_in,
                              void* d_out, int out_size, void* d_ws, size_t ws_size,
                              hipStream_t stream) {
  const float* in = (const float*)d_in[0];
  float* out = (float*)d_out;
  u64* wsw = (u64*)d_ws;                 // need 3 * 110592 * 8 B = 2.65 MB
  u64* maskP = wsw;
  u64* skelZY = wsw + NWVOL;
  u64* skelX = wsw + 2 * NWVOL;

  init_pack<<<1728, 256, 0, stream>>>(in, maskP, skelZY, skelX);
  thin_all<<<D + H + W, 1024, 0, stream>>>(maskP, skelZY, skelX);
  transpose_or<<<(NWVOL + 255) / 256, 256, 0, stream>>>(skelX, skelZY);
  dilate_expand<<<(NVOX / 4 + 255) / 256, 256, 0, stream>>>(maskP, skelZY, out);
}